// Round 1
// baseline (177.875 us; speedup 1.0000x reference)
//
#include <hip/hip_runtime.h>
#include <hip/hip_bf16.h>
#include <math.h>

// ---------------------------------------------------------------------------
// Math note: in the reference, softmax(A, axis=2) followed by
// sum(A, axis=2, keepdims=True) * V is exactly V (softmax sums to 1).
// So the whole attention block collapses to AV = V = X@Wv + bv.
// Pipeline: X1 = LN(X + X@Wv + bv); out = LN(X1 + relu(X1@W1+b1)@W2 + b2)
// ---------------------------------------------------------------------------

typedef __bf16 bf16x8 __attribute__((ext_vector_type(8)));
typedef float f32x4 __attribute__((ext_vector_type(4)));

#define BM 128
#define BN 128
#define BK 32

__device__ inline void gload_lds16(const __hip_bfloat16* g, void* lds) {
  __builtin_amdgcn_global_load_lds(
      (const __attribute__((address_space(1))) void*)g,
      (__attribute__((address_space(3))) void*)lds, 16, 0, 0);
}

// C = A(MxK,bf16) @ Bt(NxK,bf16)^T with epilogue:
// EPI==1: +bias +fp32 residual -> bf16
// EPI==2: +bias, relu          -> bf16
// EPI==3: +bias +bf16 residual -> bf16
template <int EPI>
__global__ __launch_bounds__(256, 2) void gemm_bt(
    const __hip_bfloat16* __restrict__ A, const __hip_bfloat16* __restrict__ Bt,
    __hip_bfloat16* __restrict__ C, const float* __restrict__ bias,
    const float* __restrict__ residf, const __hip_bfloat16* __restrict__ residb,
    int M, int N, int K) {
  __shared__ __align__(16) __hip_bfloat16 lA[BM * BK];
  __shared__ __align__(16) __hip_bfloat16 lB[BN * BK];

  const int t = threadIdx.x;
  const int wave = t >> 6;
  const int lane = t & 63;
  const int rowBase = blockIdx.x * BM;
  const int colBase = blockIdx.y * BN;

  const int wr = wave >> 1, wc = wave & 1;   // 2x2 waves, each owns 64x64
  const int l16 = lane & 15, lk = lane >> 4; // frag row / k-group

  f32x4 acc[4][4];
#pragma unroll
  for (int m = 0; m < 4; ++m)
#pragma unroll
    for (int n = 0; n < 4; ++n) acc[m][n] = (f32x4){0.f, 0.f, 0.f, 0.f};

  // staging map: thread t -> row t/4 (within 64-row half), k-chunk (t%4)*8
  const int sr = t >> 2;
  const int sk = (t & 3) * 8;
  const __hip_bfloat16* gA = A + (size_t)(rowBase + sr) * K + sk;
  const __hip_bfloat16* gB = Bt + (size_t)(colBase + sr) * K + sk;

  for (int k0 = 0; k0 < K; k0 += BK) {
    gload_lds16(gA + k0, (char*)lA + wave * 1024);
    gload_lds16(gA + k0 + (size_t)64 * K, (char*)lA + 4096 + wave * 1024);
    gload_lds16(gB + k0, (char*)lB + wave * 1024);
    gload_lds16(gB + k0 + (size_t)64 * K, (char*)lB + 4096 + wave * 1024);
    __syncthreads();

    bf16x8 af[4], bfr[4];
#pragma unroll
    for (int m = 0; m < 4; ++m)
      af[m] = *(const bf16x8*)&lA[(wr * 64 + m * 16 + l16) * BK + lk * 8];
#pragma unroll
    for (int n = 0; n < 4; ++n)
      bfr[n] = *(const bf16x8*)&lB[(wc * 64 + n * 16 + l16) * BK + lk * 8];
#pragma unroll
    for (int m = 0; m < 4; ++m)
#pragma unroll
      for (int n = 0; n < 4; ++n)
        acc[m][n] = __builtin_amdgcn_mfma_f32_16x16x32_bf16(af[m], bfr[n],
                                                            acc[m][n], 0, 0, 0);
    __syncthreads();
  }

  // epilogue: C/D layout col=lane&15, row=(lane>>4)*4+reg (verified m89)
#pragma unroll
  for (int m = 0; m < 4; ++m) {
#pragma unroll
    for (int n = 0; n < 4; ++n) {
#pragma unroll
      for (int j = 0; j < 4; ++j) {
        int r = rowBase + wr * 64 + m * 16 + lk * 4 + j;
        int c = colBase + wc * 64 + n * 16 + l16;
        size_t idx = (size_t)r * N + c;
        float v = acc[m][n][j] + bias[c];
        if (EPI == 1) v += residf[idx];
        if (EPI == 2) v = fmaxf(v, 0.f);
        if (EPI == 3) v += __bfloat162float(residb[idx]);
        C[idx] = __float2bfloat16(v);
      }
    }
  }
}

// LayerNorm over D=768 (biased variance, no eps), one block per row.
template <bool FINAL>
__global__ __launch_bounds__(256) void ln_kernel(
    const __hip_bfloat16* __restrict__ Y, __hip_bfloat16* __restrict__ outb,
    float* __restrict__ outf) {
  const int D = 768;
  const size_t base = (size_t)blockIdx.x * D;
  const int t = threadIdx.x;
  float v0 = __bfloat162float(Y[base + t]);
  float v1 = __bfloat162float(Y[base + t + 256]);
  float v2 = __bfloat162float(Y[base + t + 512]);
  float s = v0 + v1 + v2;
  float q = v0 * v0 + v1 * v1 + v2 * v2;
#pragma unroll
  for (int off = 32; off > 0; off >>= 1) {
    s += __shfl_down(s, off);
    q += __shfl_down(q, off);
  }
  __shared__ float red[8];
  __shared__ float stats[2];
  const int wave = t >> 6, lane = t & 63;
  if (lane == 0) {
    red[wave] = s;
    red[4 + wave] = q;
  }
  __syncthreads();
  if (t == 0) {
    float S = red[0] + red[1] + red[2] + red[3];
    float Q = red[4] + red[5] + red[6] + red[7];
    float mu = S * (1.f / 768.f);
    float var = Q * (1.f / 768.f) - mu * mu;
    stats[0] = mu;
    stats[1] = 1.f / sqrtf(var);
  }
  __syncthreads();
  float mu = stats[0], rs = stats[1];
  if (FINAL) {
    outf[base + t] = (v0 - mu) * rs;
    outf[base + t + 256] = (v1 - mu) * rs;
    outf[base + t + 512] = (v2 - mu) * rs;
  } else {
    outb[base + t] = __float2bfloat16((v0 - mu) * rs);
    outb[base + t + 256] = __float2bfloat16((v1 - mu) * rs);
    outb[base + t + 512] = __float2bfloat16((v2 - mu) * rs);
  }
}

// fp32 -> bf16 cast, 4 elements/thread
__global__ __launch_bounds__(256) void cast_bf16_kernel(
    const float* __restrict__ in, __hip_bfloat16* __restrict__ out, int n4) {
  int i = blockIdx.x * blockDim.x + threadIdx.x;
  if (i >= n4) return;
  float4 v = reinterpret_cast<const float4*>(in)[i];
  __hip_bfloat16 h0 = __float2bfloat16(v.x), h1 = __float2bfloat16(v.y);
  __hip_bfloat16 h2 = __float2bfloat16(v.z), h3 = __float2bfloat16(v.w);
  ushort4 o;
  o.x = *reinterpret_cast<unsigned short*>(&h0);
  o.y = *reinterpret_cast<unsigned short*>(&h1);
  o.z = *reinterpret_cast<unsigned short*>(&h2);
  o.w = *reinterpret_cast<unsigned short*>(&h3);
  reinterpret_cast<ushort4*>(out)[i] = o;
}

// W (KxN fp32) -> Wt (NxK bf16)
__global__ __launch_bounds__(256) void transpose_cast(
    const float* __restrict__ W, __hip_bfloat16* __restrict__ Wt, int K, int N) {
  __shared__ float tile[32][33];
  const int t = threadIdx.x;
  const int tx = t & 31;
  const int ty = t >> 5; // 0..7
  const int n0 = blockIdx.x * 32;
  const int k0 = blockIdx.y * 32;
#pragma unroll
  for (int i = 0; i < 32; i += 8)
    tile[ty + i][tx] = W[(size_t)(k0 + ty + i) * N + n0 + tx];
  __syncthreads();
#pragma unroll
  for (int i = 0; i < 32; i += 8)
    Wt[(size_t)(n0 + ty + i) * K + k0 + tx] = __float2bfloat16(tile[tx][ty + i]);
}

extern "C" void kernel_launch(void* const* d_in, const int* in_sizes, int n_in,
                              void* d_out, int out_size, void* d_ws,
                              size_t ws_size, hipStream_t stream) {
  const float* X = (const float*)d_in[0];
  const float* Wv = (const float*)d_in[5];
  const float* bv = (const float*)d_in[6];
  const float* W1 = (const float*)d_in[7];
  const float* b1 = (const float*)d_in[8];
  const float* W2 = (const float*)d_in[9];
  const float* b2 = (const float*)d_in[10];
  float* out = (float*)d_out;

  const int M = 4 * 2048; // 8192 rows
  const int D = 768, H = 3072;

  // workspace layout (bytes): total 98,697,216
  char* ws = (char*)d_ws;
  __hip_bfloat16* Xb = (__hip_bfloat16*)(ws);               // M*D bf16
  __hip_bfloat16* Wvt = (__hip_bfloat16*)(ws + 12582912);   // D*D
  __hip_bfloat16* W1t = (__hip_bfloat16*)(ws + 13762560);   // H*D (W1^T)
  __hip_bfloat16* W2t = (__hip_bfloat16*)(ws + 18481152);   // D*H (W2^T)
  __hip_bfloat16* Yb = (__hip_bfloat16*)(ws + 23199744);    // M*D
  __hip_bfloat16* X1b = (__hip_bfloat16*)(ws + 35782656);   // M*D
  __hip_bfloat16* Gb = (__hip_bfloat16*)(ws + 48365568);    // M*H
  __hip_bfloat16* Y2b = Xb; // Xb dead after GEMM1 -> reuse

  cast_bf16_kernel<<<dim3((M * D / 4 + 255) / 256), 256, 0, stream>>>(X, Xb,
                                                                      M * D / 4);
  transpose_cast<<<dim3(D / 32, D / 32), 256, 0, stream>>>(Wv, Wvt, D, D);
  transpose_cast<<<dim3(H / 32, D / 32), 256, 0, stream>>>(W1, W1t, D, H);
  transpose_cast<<<dim3(D / 32, H / 32), 256, 0, stream>>>(W2, W2t, H, D);

  // Y = X + X@Wv + bv
  gemm_bt<1><<<dim3(M / BM, D / BN), 256, 0, stream>>>(Xb, Wvt, Yb, bv, X,
                                                       nullptr, M, D, D);
  // X1 = LN(Y)
  ln_kernel<false><<<M, 256, 0, stream>>>(Yb, X1b, nullptr);
  // G = relu(X1@W1 + b1)
  gemm_bt<2><<<dim3(M / BM, H / BN), 256, 0, stream>>>(X1b, W1t, Gb, b1,
                                                       nullptr, nullptr, M, H, D);
  // Y2 = X1 + G@W2 + b2
  gemm_bt<3><<<dim3(M / BM, D / BN), 256, 0, stream>>>(Gb, W2t, Y2b, b2,
                                                       nullptr, X1b, M, D, H);
  // out = LN(Y2)
  ln_kernel<true><<<M, 256, 0, stream>>>(Y2b, nullptr, out);
}

// Round 2
// 154.362 us; speedup vs baseline: 1.1523x; 1.1523x over previous
//
#include <hip/hip_runtime.h>
#include <hip/hip_bf16.h>
#include <math.h>

// ---------------------------------------------------------------------------
// Math note: softmax(A, axis=2) then sum(A, axis=2, keepdims=True) * V == V.
// Pipeline: X1 = LN(X + X@Wv + bv); out = LN(X1 + relu(X1@W1+b1)@W2 + b2)
//
// Round-2 structure:
//  - GEMM1 (8192x768x768)  split-K x2 -> bf16 partials P1, fused reduce in LN1
//  - GEMM2 (8192x3072x768) full K, relu+bias epilogue
//  - GEMM3 (8192x768x3072) split-K x2 -> bf16 partials P3, fused reduce in LN2
//  - gemm_bt: double-buffered LDS, prefetch-issue-first (T3-minimum),
//    bank-swizzled staging (pre-swizzled global source, rule 21)
// ---------------------------------------------------------------------------

typedef __bf16 bf16x8 __attribute__((ext_vector_type(8)));
typedef float f32x4 __attribute__((ext_vector_type(4)));

#define BM 128
#define BN 128
#define BK 32

__device__ inline void gload_lds16(const __hip_bfloat16* g, void* lds) {
  __builtin_amdgcn_global_load_lds(
      (const __attribute__((address_space(1))) void*)g,
      (__attribute__((address_space(3))) void*)lds, 16, 0, 0);
}

__device__ inline float bf2f(unsigned short u) {
  union { unsigned int i; float f; } x;
  x.i = ((unsigned int)u) << 16;
  return x.f;
}

// C = A(MxK,bf16) @ Bt(NxK,bf16)^T  over K-range [z*Ksub, (z+1)*Ksub)
// EPI==0: raw bf16 partial (C += z*M*N)
// EPI==2: +bias, relu -> bf16
template <int EPI>
__global__ __launch_bounds__(256, 4) void gemm_bt(
    const __hip_bfloat16* __restrict__ A, const __hip_bfloat16* __restrict__ Bt,
    __hip_bfloat16* __restrict__ C, const float* __restrict__ bias,
    int M, int N, int K, int Ksub) {
  __shared__ __align__(16) __hip_bfloat16 lA[2][BM * BK];
  __shared__ __align__(16) __hip_bfloat16 lB[2][BN * BK];

  const int t = threadIdx.x;
  const int wave = t >> 6;
  const int lane = t & 63;
  const int rowBase = blockIdx.x * BM;
  const int colBase = blockIdx.y * BN;
  const int kBase = blockIdx.z * Ksub;

  const int wr = wave >> 1, wc = wave & 1;   // 2x2 waves, each owns 64x64
  const int l16 = lane & 15, lk = lane >> 4; // frag row / k-slot

  f32x4 acc[4][4];
#pragma unroll
  for (int m = 0; m < 4; ++m)
#pragma unroll
    for (int n = 0; n < 4; ++n) acc[m][n] = (f32x4){0.f, 0.f, 0.f, 0.f};

  // staging map: thread t -> row t/4, k-chunk swizzled so that the LINEAR
  // LDS layout [row][slot] holds data for logical slot (slot ^ ((row>>1)&3)).
  const int sr = t >> 2;
  const int sk = ((t & 3) ^ ((t >> 3) & 3)) * 8;
  const __hip_bfloat16* gA = A + (size_t)(rowBase + sr) * K + kBase + sk;
  const __hip_bfloat16* gB = Bt + (size_t)(colBase + sr) * K + kBase + sk;

#define STAGE(buf, k0)                                                      \
  do {                                                                      \
    gload_lds16(gA + (k0), (char*)&lA[buf][0] + wave * 1024);               \
    gload_lds16(gA + (k0) + (size_t)64 * K,                                 \
                (char*)&lA[buf][0] + 4096 + wave * 1024);                   \
    gload_lds16(gB + (k0), (char*)&lB[buf][0] + wave * 1024);               \
    gload_lds16(gB + (k0) + (size_t)64 * K,                                 \
                (char*)&lB[buf][0] + 4096 + wave * 1024);                   \
  } while (0)

  const int nt = Ksub / BK;
  STAGE(0, 0);
  __syncthreads();

  // per-lane physical k-slot for ds_read: logical slot lk at row r lives at
  // slot lk ^ ((r>>1)&3); for r = base16*16 + l16 this is lk ^ ((l16>>1)&3).
  const int kx = (lk ^ ((l16 >> 1) & 3)) * 8;

  int cur = 0;
  for (int it = 0; it < nt; ++it) {
    if (it + 1 < nt) STAGE(cur ^ 1, (it + 1) * BK);

    bf16x8 af[4], bfr[4];
#pragma unroll
    for (int m = 0; m < 4; ++m)
      af[m] = *(const bf16x8*)&lA[cur][(wr * 64 + m * 16 + l16) * BK + kx];
#pragma unroll
    for (int n = 0; n < 4; ++n)
      bfr[n] = *(const bf16x8*)&lB[cur][(wc * 64 + n * 16 + l16) * BK + kx];

    asm volatile("s_waitcnt lgkmcnt(0)" ::: "memory");
    __builtin_amdgcn_sched_barrier(0);
#pragma unroll
    for (int m = 0; m < 4; ++m)
#pragma unroll
      for (int n = 0; n < 4; ++n)
        acc[m][n] = __builtin_amdgcn_mfma_f32_16x16x32_bf16(af[m], bfr[n],
                                                            acc[m][n], 0, 0, 0);
    __syncthreads();  // drains vmcnt(0): next-tile stage complete
    cur ^= 1;
  }
#undef STAGE

  __hip_bfloat16* Cz = C + (size_t)blockIdx.z * M * N;
  // C/D layout: col=lane&15, row=(lane>>4)*4+reg (verified m89)
#pragma unroll
  for (int m = 0; m < 4; ++m) {
#pragma unroll
    for (int n = 0; n < 4; ++n) {
#pragma unroll
      for (int j = 0; j < 4; ++j) {
        int r = rowBase + wr * 64 + m * 16 + lk * 4 + j;
        int c = colBase + wc * 64 + n * 16 + l16;
        size_t idx = (size_t)r * N + c;
        float v = acc[m][n][j];
        if (EPI == 2) v = fmaxf(v + bias[c], 0.f);
        Cz[idx] = __float2bfloat16(v);
      }
    }
  }
}

// Fused: y = P0 + P1 + resid + bias;  out = (y - mean(y)) / sqrt(var(y))
// One wave per row (D=768 -> 12 elems/lane), 4 rows per block.
template <bool FINAL>
__global__ __launch_bounds__(256) void ln_fuse2(
    const __hip_bfloat16* __restrict__ P0, const __hip_bfloat16* __restrict__ P1,
    const float* __restrict__ residf, const __hip_bfloat16* __restrict__ residb,
    const float* __restrict__ bias, __hip_bfloat16* __restrict__ outb,
    float* __restrict__ outf) {
  const int wave = threadIdx.x >> 6, lane = threadIdx.x & 63;
  const size_t base = ((size_t)blockIdx.x * 4 + wave) * 768;

  float v[12];
  float s = 0.f, q = 0.f;
#pragma unroll
  for (int c = 0; c < 3; ++c) {
    const int col = c * 256 + lane * 4;
    ushort4 a = *reinterpret_cast<const ushort4*>(&P0[base + col]);
    ushort4 b = *reinterpret_cast<const ushort4*>(&P1[base + col]);
    float4 bs = *reinterpret_cast<const float4*>(&bias[col]);
    float r0, r1, r2, r3;
    if (FINAL) {
      ushort4 rb = *reinterpret_cast<const ushort4*>(&residb[base + col]);
      r0 = bf2f(rb.x); r1 = bf2f(rb.y); r2 = bf2f(rb.z); r3 = bf2f(rb.w);
    } else {
      float4 rf = *reinterpret_cast<const float4*>(&residf[base + col]);
      r0 = rf.x; r1 = rf.y; r2 = rf.z; r3 = rf.w;
    }
    float y0 = bf2f(a.x) + bf2f(b.x) + r0 + bs.x;
    float y1 = bf2f(a.y) + bf2f(b.y) + r1 + bs.y;
    float y2 = bf2f(a.z) + bf2f(b.z) + r2 + bs.z;
    float y3 = bf2f(a.w) + bf2f(b.w) + r3 + bs.w;
    v[c * 4 + 0] = y0; v[c * 4 + 1] = y1; v[c * 4 + 2] = y2; v[c * 4 + 3] = y3;
    s += y0 + y1 + y2 + y3;
    q += y0 * y0 + y1 * y1 + y2 * y2 + y3 * y3;
  }
#pragma unroll
  for (int off = 32; off; off >>= 1) {
    s += __shfl_xor(s, off);
    q += __shfl_xor(q, off);
  }
  const float mu = s * (1.f / 768.f);
  const float rs = rsqrtf(q * (1.f / 768.f) - mu * mu);
#pragma unroll
  for (int c = 0; c < 3; ++c) {
    const int col = c * 256 + lane * 4;
    if (FINAL) {
      float4 o;
      o.x = (v[c * 4 + 0] - mu) * rs;
      o.y = (v[c * 4 + 1] - mu) * rs;
      o.z = (v[c * 4 + 2] - mu) * rs;
      o.w = (v[c * 4 + 3] - mu) * rs;
      *reinterpret_cast<float4*>(&outf[base + col]) = o;
    } else {
      __hip_bfloat16 h0 = __float2bfloat16((v[c * 4 + 0] - mu) * rs);
      __hip_bfloat16 h1 = __float2bfloat16((v[c * 4 + 1] - mu) * rs);
      __hip_bfloat16 h2 = __float2bfloat16((v[c * 4 + 2] - mu) * rs);
      __hip_bfloat16 h3 = __float2bfloat16((v[c * 4 + 3] - mu) * rs);
      ushort4 o;
      o.x = *reinterpret_cast<unsigned short*>(&h0);
      o.y = *reinterpret_cast<unsigned short*>(&h1);
      o.z = *reinterpret_cast<unsigned short*>(&h2);
      o.w = *reinterpret_cast<unsigned short*>(&h3);
      *reinterpret_cast<ushort4*>(&outb[base + col]) = o;
    }
  }
}

// fp32 -> bf16 cast, 4 elements/thread
__global__ __launch_bounds__(256) void cast_bf16_kernel(
    const float* __restrict__ in, __hip_bfloat16* __restrict__ out, int n4) {
  int i = blockIdx.x * blockDim.x + threadIdx.x;
  if (i >= n4) return;
  float4 v = reinterpret_cast<const float4*>(in)[i];
  __hip_bfloat16 h0 = __float2bfloat16(v.x), h1 = __float2bfloat16(v.y);
  __hip_bfloat16 h2 = __float2bfloat16(v.z), h3 = __float2bfloat16(v.w);
  ushort4 o;
  o.x = *reinterpret_cast<unsigned short*>(&h0);
  o.y = *reinterpret_cast<unsigned short*>(&h1);
  o.z = *reinterpret_cast<unsigned short*>(&h2);
  o.w = *reinterpret_cast<unsigned short*>(&h3);
  reinterpret_cast<ushort4*>(out)[i] = o;
}

// W (KxN fp32) -> Wt (NxK bf16)
__global__ __launch_bounds__(256) void transpose_cast(
    const float* __restrict__ W, __hip_bfloat16* __restrict__ Wt, int K, int N) {
  __shared__ float tile[32][33];
  const int t = threadIdx.x;
  const int tx = t & 31;
  const int ty = t >> 5; // 0..7
  const int n0 = blockIdx.x * 32;
  const int k0 = blockIdx.y * 32;
#pragma unroll
  for (int i = 0; i < 32; i += 8)
    tile[ty + i][tx] = W[(size_t)(k0 + ty + i) * N + n0 + tx];
  __syncthreads();
#pragma unroll
  for (int i = 0; i < 32; i += 8)
    Wt[(size_t)(n0 + ty + i) * K + k0 + tx] = __float2bfloat16(tile[tx][ty + i]);
}

extern "C" void kernel_launch(void* const* d_in, const int* in_sizes, int n_in,
                              void* d_out, int out_size, void* d_ws,
                              size_t ws_size, hipStream_t stream) {
  const float* X = (const float*)d_in[0];
  const float* Wv = (const float*)d_in[5];
  const float* bv = (const float*)d_in[6];
  const float* W1 = (const float*)d_in[7];
  const float* b1 = (const float*)d_in[8];
  const float* W2 = (const float*)d_in[9];
  const float* b2 = (const float*)d_in[10];
  float* out = (float*)d_out;

  const int M = 4 * 2048; // 8192 rows
  const int D = 768, H = 3072;

  // workspace layout (bytes), total 92,798,976:
  //  [0, 25165824)        : P3 (2 bf16 partials of GEMM3) -- overlaps Xb/Wvt/W1t
  //    [0, 12582912)      : Xb           (dead after GEMM1)
  //    [12582912, ...)    : Wvt 1179648  (dead after GEMM1)
  //    [13762560, ...)    : W1t 4718592  (dead after GEMM2)
  //  [25165824, 29884416) : W2t
  //  [29884416, 42467328) : X1b
  //  [42467328, 92798976) : Gb (8192x3072 bf16)
  //    [42467328, 67633152): P1 (2 bf16 partials of GEMM1, dead before GEMM2)
  char* ws = (char*)d_ws;
  __hip_bfloat16* P3 = (__hip_bfloat16*)(ws);
  __hip_bfloat16* Xb = (__hip_bfloat16*)(ws);
  __hip_bfloat16* Wvt = (__hip_bfloat16*)(ws + 12582912);
  __hip_bfloat16* W1t = (__hip_bfloat16*)(ws + 13762560);
  __hip_bfloat16* W2t = (__hip_bfloat16*)(ws + 25165824);
  __hip_bfloat16* X1b = (__hip_bfloat16*)(ws + 29884416);
  __hip_bfloat16* Gb = (__hip_bfloat16*)(ws + 42467328);
  __hip_bfloat16* P1 = (__hip_bfloat16*)(ws + 42467328);

  cast_bf16_kernel<<<dim3((M * D / 4 + 255) / 256), 256, 0, stream>>>(X, Xb,
                                                                      M * D / 4);
  transpose_cast<<<dim3(D / 32, D / 32), 256, 0, stream>>>(Wv, Wvt, D, D);
  transpose_cast<<<dim3(H / 32, D / 32), 256, 0, stream>>>(W1, W1t, D, H);
  transpose_cast<<<dim3(D / 32, H / 32), 256, 0, stream>>>(W2, W2t, H, D);

  // GEMM1 split-K x2: P1[z] = Xb @ Wvt  (K-range z)
  gemm_bt<0><<<dim3(M / BM, D / BN, 2), 256, 0, stream>>>(Xb, Wvt, P1, nullptr,
                                                          M, D, D, D / 2);
  // X1 = LN(P1_0 + P1_1 + X + bv)
  ln_fuse2<false><<<M / 4, 256, 0, stream>>>(P1, P1 + (size_t)M * D, X, nullptr,
                                             bv, X1b, nullptr);
  // G = relu(X1@W1 + b1)
  gemm_bt<2><<<dim3(M / BM, H / BN, 1), 256, 0, stream>>>(X1b, W1t, Gb, b1, M,
                                                          H, D, D);
  // GEMM3 split-K x2: P3[z] = Gb @ W2t
  gemm_bt<0><<<dim3(M / BM, D / BN, 2), 256, 0, stream>>>(Gb, W2t, P3, nullptr,
                                                          M, D, H, H / 2);
  // out = LN(P3_0 + P3_1 + X1b + b2)
  ln_fuse2<true><<<M / 4, 256, 0, stream>>>(P3, P3 + (size_t)M * D, nullptr,
                                            X1b, b2, nullptr, out);
}